// Round 3
// baseline (183.902 us; speedup 1.0000x reference)
//
#include <hip/hip_runtime.h>

#define NDRUG 846
#define EDIM  64
#define SNB   1024
#define RLEN  100

// ---- workspace layout (floats) ----
#define XBUF_OFF  0
#define B2SUM_OFF (NDRUG*EDIM)

// ---------------------------------------------------------------------------
// prep2: b2sum[s] = sum_f b2[s][f]   (16 blocks x 256 thr)
// ---------------------------------------------------------------------------
__global__ __launch_bounds__(256) void prep2(const float* __restrict__ b2,
                                             float* __restrict__ b2sum)
{
  int t = threadIdx.x;
  int s = blockIdx.x*64 + (t >> 2);
  int q = t & 3;
  const float4* p = reinterpret_cast<const float4*>(b2 + (size_t)s*EDIM) + q*4;
  float4 a = p[0], b = p[1], c = p[2], d = p[3];
  float v = (a.x+a.y+a.z+a.w) + (b.x+b.y+b.z+b.w)
          + (c.x+c.y+c.z+c.w) + (d.x+d.y+d.z+d.w);
  v += __shfl_xor(v, 1);
  v += __shfl_xor(v, 2);
  if (q == 0) b2sum[s] = v;
}

// ---------------------------------------------------------------------------
// gnn_main: one block (512 thr, 8 waves) per drug.
// LDS ~33 KB -> 4 blocks/CU -> 1024 resident slots >= 846 blocks (no tail).
// __launch_bounds__(512,8) forces VGPR<=64 so all 32 waves/CU are resident.
// ---------------------------------------------------------------------------
__global__ __launch_bounds__(512, 8) void gnn_main(
    const int*   __restrict__ adj_tail,  const int* __restrict__ adj_relation,
    const float* __restrict__ drug_table, const float* __restrict__ rela_table,
    const float* __restrict__ ent_table, const float* __restrict__ W1,
    const float* __restrict__ W2,        const float* __restrict__ b1,
    const float* __restrict__ lin_W,     const float* __restrict__ lin_b,
    const float* __restrict__ b2sum,     float* __restrict__ xbuf)
{
  __shared__ __align__(16) float lds[8352];
  float* g_s     = lds;          // [100][66] = 6600 (pad 66: 4-way max on writes)
  float* score_s = lds + 6600;   // 1024
  float* red_s   = lds + 7624;   // 512 (phase-4 partials, then phase-5 partials)
  float* went_s  = lds + 8136;   // 64
  float* demb_s  = lds + 8200;   // 64
  float* w2sum_s = lds + 8264;   // 64
  float* mred    = lds + 8328;   // 16

  int n  = blockIdx.x;
  int t  = threadIdx.x;
  int w8 = __builtin_amdgcn_readfirstlane(t >> 6);   // wave 0..7 (uniform)
  int ln = t & 63;

  // ---- phase 0: demb_s (for phase 5), w2sum[e] = sum_f W2[n][e][f] ---------
  if (t < EDIM) demb_s[t] = drug_table[(size_t)n*EDIM + t];
  {
    const float4* w2p4 = reinterpret_cast<const float4*>(W2 + (size_t)n*4096);
    float4 a = w2p4[t*2], b = w2p4[t*2+1];
    float s8 = (a.x+a.y+a.z+a.w) + (b.x+b.y+b.z+b.w);
    s8 += __shfl_xor(s8, 1);
    s8 += __shfl_xor(s8, 2);
    s8 += __shfl_xor(s8, 4);
    if ((t & 7) == 0) w2sum_s[t >> 3] = s8;   // e = t>>3
  }
  __syncthreads();

  // ---- phase 1: g[r][f=ln] = sum_e (demb[e]*rela[r][e]) * W1[n][e][f] ------
  // lane = f; wave w8 owns r in [w8*13, w8*13+13) clamped to <100.
  // demb folded into w1c; rela read via wave-uniform scalar loads (L2-hot).
  // e split in two halves of 32 to keep w1c in 32 VGPRs (+acc[13]).
  {
    const float* w1p   = W1 + (size_t)n*4096 + ln;
    const float* dembg = drug_table + (size_t)n*EDIM;   // uniform -> s_load
    float acc[13];
    int rbase = w8*13;
    {
      float w1c[32];
      #pragma unroll
      for (int e = 0; e < 32; ++e) w1c[e] = w1p[e*64] * dembg[e];
      #pragma unroll
      for (int rr = 0; rr < 13; ++rr) {
        int r = rbase + rr; int rc = (r < RLEN) ? r : RLEN-1;
        const float* rp = rela_table + (size_t)rc*EDIM;  // uniform -> s_load
        float a = 0.f;
        #pragma unroll
        for (int e = 0; e < 32; ++e) a = fmaf(rp[e], w1c[e], a);
        acc[rr] = a;
      }
    }
    {
      float w1c[32];
      #pragma unroll
      for (int e = 0; e < 32; ++e) w1c[e] = w1p[(e+32)*64] * dembg[e+32];
      #pragma unroll
      for (int rr = 0; rr < 13; ++rr) {
        int r = rbase + rr; int rc = (r < RLEN) ? r : RLEN-1;
        const float* rp = rela_table + (size_t)rc*EDIM + 32;
        float a = acc[rr];
        #pragma unroll
        for (int e = 0; e < 32; ++e) a = fmaf(rp[e], w1c[e], a);
        if (r < RLEN) g_s[r*66 + ln] = a;   // lanes contiguous: conflict-free
      }
    }
  }
  __syncthreads();

  // ---- phase 2: score[s] = sum_f relu(g[rel_s][f]+b1[s][f])*w2sum[f]+b2sum[s]
  // 4 lanes per s (fq covers f = jj*16 + fq*4 + c); fully unrolled so the 8
  // independent rel/b1 loads pipeline.
  {
    int fq = ln & 3;
    int sh = t >> 2;                         // 0..127
    float w2r[16];
    #pragma unroll
    for (int jj = 0; jj < 4; ++jj) {
      float4 v4 = *reinterpret_cast<const float4*>(w2sum_s + jj*16 + fq*4);
      w2r[jj*4+0] = v4.x; w2r[jj*4+1] = v4.y; w2r[jj*4+2] = v4.z; w2r[jj*4+3] = v4.w;
    }
    #pragma unroll
    for (int it = 0; it < 8; ++it) {
      int s   = it*128 + sh;
      int rel = adj_relation[(size_t)n*SNB + s];
      const float4* b1r = reinterpret_cast<const float4*>(b1 + (size_t)s*EDIM);
      const float2* g2  = reinterpret_cast<const float2*>(g_s + rel*66);
      float a2 = 0.f;
      #pragma unroll
      for (int jj = 0; jj < 4; ++jj) {
        float4 bv = b1r[jj*4 + fq];          // coalesced: 4 lanes cover 64B
        float2 ga = g2[jj*8 + fq*2];
        float2 gb = g2[jj*8 + fq*2 + 1];
        a2 = fmaf(fmaxf(ga.x + bv.x, 0.f), w2r[jj*4+0], a2);
        a2 = fmaf(fmaxf(ga.y + bv.y, 0.f), w2r[jj*4+1], a2);
        a2 = fmaf(fmaxf(gb.x + bv.z, 0.f), w2r[jj*4+2], a2);
        a2 = fmaf(fmaxf(gb.y + bv.w, 0.f), w2r[jj*4+3], a2);
      }
      a2 += __shfl_xor(a2, 1);
      a2 += __shfl_xor(a2, 2);
      if (fq == 0) score_s[s] = a2 + b2sum[s];
    }
  }
  __syncthreads();

  // ---- phase 3: softmax over 1024 (2 scores/thread; wave w8 owns chunks
  //      s = w8*64+ln and s = 512+w8*64+ln) ---------------------------------
  float av0, av1;
  {
    float s0 = score_s[t], s1 = score_s[512 + t];
    float m = fmaxf(s0, s1);
    #pragma unroll
    for (int o = 32; o >= 1; o >>= 1) m = fmaxf(m, __shfl_xor(m, o));
    if (ln == 0) mred[w8] = m;
    __syncthreads();
    float M = mred[0];
    #pragma unroll
    for (int k = 1; k < 8; ++k) M = fmaxf(M, mred[k]);
    float e0 = __expf(s0 - M), e1 = __expf(s1 - M);
    float sum = e0 + e1;
    #pragma unroll
    for (int o = 32; o >= 1; o >>= 1) sum += __shfl_xor(sum, o);
    if (ln == 0) mred[8 + w8] = sum;
    __syncthreads();
    float S = mred[8];
    #pragma unroll
    for (int k = 9; k < 16; ++k) S += mred[k];
    float inv = 1.0f / S;
    av0 = e0*inv; av1 = e1*inv;
  }

  // ---- phase 4: weighted_ent — each wave gathers its OWN active neighbors
  // (ballot of its 2 chunks; attn broadcast from owning lane via __shfl).
  {
    unsigned long long m0 = __ballot(av0 > 2e-9f);
    unsigned long long m1 = __ballot(av1 > 2e-9f);
    float acc4 = 0.f;
    const int* tails = adj_tail + (size_t)n*SNB;
    while (m0) {
      int b = __ffsll(m0) - 1; m0 &= m0 - 1;        // wave-uniform loop
      int s = w8*64 + b;
      float av = __shfl(av0, b);
      acc4 = fmaf(av, ent_table[(size_t)tails[s]*EDIM + ln], acc4);
    }
    while (m1) {
      int b = __ffsll(m1) - 1; m1 &= m1 - 1;
      int s = 512 + w8*64 + b;
      float av = __shfl(av1, b);
      acc4 = fmaf(av, ent_table[(size_t)tails[s]*EDIM + ln], acc4);
    }
    red_s[w8*64 + ln] = acc4;
  }
  __syncthreads();
  if (t < EDIM) {
    float w = red_s[t];
    #pragma unroll
    for (int k = 1; k < 8; ++k) w += red_s[k*64 + t];
    went_s[t] = w;
  }
  __syncthreads();

  // ---- phase 5: x = relu([went, demb] @ lin_W^T + lin_b) -------------------
  {
    float acc = 0.f;
    const float* lw = lin_W + (size_t)ln*128 + w8*16;
    #pragma unroll
    for (int k = 0; k < 16; ++k) {
      int kk = w8*16 + k;
      float cv = (kk < 64) ? went_s[kk] : demb_s[kk - 64];
      acc = fmaf(cv, lw[k], acc);
    }
    red_s[w8*64 + ln] = acc;
  }
  __syncthreads();
  if (t < EDIM) {
    float x = lin_b[t];
    #pragma unroll
    for (int w = 0; w < 8; ++w) x += red_s[w*64 + t];
    xbuf[(size_t)n*EDIM + t] = fmaxf(x, 0.f);
  }
}

// ---------------------------------------------------------------------------
// bn: one block per channel e — stats + apply fused
// ---------------------------------------------------------------------------
__global__ __launch_bounds__(256) void bn_kernel(
    const float* __restrict__ xbuf, const float* __restrict__ gamma,
    const float* __restrict__ beta, float* __restrict__ out)
{
  __shared__ float r1[4], r2[4];
  int e = blockIdx.x, t = threadIdx.x;
  float v[4];
  float s = 0.f, s2 = 0.f;
  #pragma unroll
  for (int k = 0; k < 4; ++k) {
    int nn = t + k*256;
    v[k] = (nn < NDRUG) ? xbuf[(size_t)nn*EDIM + e] : 0.f;
    s += v[k]; s2 += v[k]*v[k];
  }
  #pragma unroll
  for (int o = 32; o >= 1; o >>= 1) { s += __shfl_xor(s, o); s2 += __shfl_xor(s2, o); }
  if ((t & 63) == 0) { r1[t >> 6] = s; r2[t >> 6] = s2; }
  __syncthreads();
  float S  = r1[0] + r1[1] + r1[2] + r1[3];
  float S2 = r2[0] + r2[1] + r2[2] + r2[3];
  float mean = S / (float)NDRUG;
  float var  = S2 / (float)NDRUG - mean*mean;
  float sc   = gamma[e] * rsqrtf(var + 1e-5f);
  float sh   = beta[e] - mean*sc;
  #pragma unroll
  for (int k = 0; k < 4; ++k) {
    int nn = t + k*256;
    if (nn < NDRUG) out[(size_t)nn*EDIM + e] = v[k]*sc + sh;
  }
}

// ---------------------------------------------------------------------------
extern "C" void kernel_launch(void* const* d_in, const int* in_sizes, int n_in,
                              void* d_out, int out_size, void* d_ws, size_t ws_size,
                              hipStream_t stream)
{
  const int*   adj_tail   = (const int*)d_in[1];
  const int*   adj_rel    = (const int*)d_in[2];
  const float* drug_table = (const float*)d_in[3];
  const float* rela_table = (const float*)d_in[4];
  const float* ent_table  = (const float*)d_in[5];
  const float* W1         = (const float*)d_in[6];
  const float* b1         = (const float*)d_in[7];
  const float* W2         = (const float*)d_in[8];
  const float* b2         = (const float*)d_in[9];
  const float* lin_W      = (const float*)d_in[10];
  const float* lin_b      = (const float*)d_in[11];
  const float* gamma      = (const float*)d_in[12];
  const float* beta       = (const float*)d_in[13];

  float* ws    = (float*)d_ws;
  float* xbuf  = ws + XBUF_OFF;
  float* b2sum = ws + B2SUM_OFF;
  float* out   = (float*)d_out;

  hipLaunchKernelGGL(prep2, dim3(16), dim3(256), 0, stream, b2, b2sum);
  hipLaunchKernelGGL(gnn_main, dim3(NDRUG), dim3(512), 0, stream,
                     adj_tail, adj_rel, drug_table, rela_table, ent_table,
                     W1, W2, b1, lin_W, lin_b, b2sum, xbuf);
  hipLaunchKernelGGL(bn_kernel, dim3(EDIM), dim3(256), 0, stream,
                     xbuf, gamma, beta, out);
}

// Round 4
// 150.146 us; speedup vs baseline: 1.2248x; 1.2248x over previous
//
#include <hip/hip_runtime.h>

#define NDRUG 846
#define EDIM  64
#define SNB   1024
#define RLEN  100

// ---- workspace layout (floats) ----
#define XBUF_OFF  0
#define B2SUM_OFF (NDRUG*EDIM)

// ---------------------------------------------------------------------------
// prep2: b2sum[s] = sum_f b2[s][f]   (16 blocks x 256 thr)
// ---------------------------------------------------------------------------
__global__ __launch_bounds__(256) void prep2(const float* __restrict__ b2,
                                             float* __restrict__ b2sum)
{
  int t = threadIdx.x;
  int s = blockIdx.x*64 + (t >> 2);
  int q = t & 3;
  const float4* p = reinterpret_cast<const float4*>(b2 + (size_t)s*EDIM) + q*4;
  float4 a = p[0], b = p[1], c = p[2], d = p[3];
  float v = (a.x+a.y+a.z+a.w) + (b.x+b.y+b.z+b.w)
          + (c.x+c.y+c.z+c.w) + (d.x+d.y+d.z+d.w);
  v += __shfl_xor(v, 1);
  v += __shfl_xor(v, 2);
  if (q == 0) b2sum[s] = v;
}

// ---------------------------------------------------------------------------
// gnn_main: one block (256 thr, 4 waves) per drug.
// LDS 32.3 KB and VGPR<=128 (launch_bounds 256,4) -> 4 blocks/CU ->
// 1024 resident block slots >= 846 -> no grid tail. No register spills
// (w1c[32] two-pass + acc[25] ~ 80 VGPR < 128).
// ---------------------------------------------------------------------------
__global__ __launch_bounds__(256, 4) void gnn_main(
    const int*   __restrict__ adj_tail,  const int* __restrict__ adj_relation,
    const float* __restrict__ drug_table, const float* __restrict__ rela_table,
    const float* __restrict__ ent_table, const float* __restrict__ W1,
    const float* __restrict__ W2,        const float* __restrict__ b1,
    const float* __restrict__ lin_W,     const float* __restrict__ lin_b,
    const float* __restrict__ b2sum,     float* __restrict__ xbuf)
{
  __shared__ __align__(16) float lds[8080];
  float* g_s     = lds;          // [100][66] = 6600 (write: 64 consec lanes, 2/bank)
  float* score_s = lds + 6600;   // 1024
  float* red_s   = lds + 7624;   // 256 (phase-4 partials, then phase-5 partials)
  float* went_s  = lds + 7880;   // 64
  float* demb_s  = lds + 7944;   // 64
  float* w2sum_s = lds + 8008;   // 64
  float* mred    = lds + 8072;   // 8

  int n  = blockIdx.x;
  int t  = threadIdx.x;
  int w4 = __builtin_amdgcn_readfirstlane(t >> 6);   // wave 0..3 (uniform)
  int ln = t & 63;

  // ---- phase 0: demb_s (phase 5), w2sum[e] = sum_f W2[n][e][f] -------------
  if (t < EDIM) demb_s[t] = drug_table[(size_t)n*EDIM + t];
  {
    int e = t >> 2, q = t & 3;
    const float4* w2p4 = reinterpret_cast<const float4*>(W2 + (size_t)n*4096);
    float4 a = w2p4[e*16 + q*4 + 0], b = w2p4[e*16 + q*4 + 1];
    float4 c = w2p4[e*16 + q*4 + 2], d = w2p4[e*16 + q*4 + 3];
    float s16 = (a.x+a.y+a.z+a.w) + (b.x+b.y+b.z+b.w)
              + (c.x+c.y+c.z+c.w) + (d.x+d.y+d.z+d.w);
    s16 += __shfl_xor(s16, 1);
    s16 += __shfl_xor(s16, 2);
    if (q == 0) w2sum_s[e] = s16;
  }
  __syncthreads();

  // ---- phase 1: g[r][f=ln] = sum_e (demb[e]*rela[r][e]) * W1[n][e][f] ------
  // lane = f; wave w4 owns r in [w4*25, w4*25+25)  (100 = 4*25 exactly).
  // demb folded into w1c (registers, coalesced loads); rela via wave-uniform
  // scalar loads. e split into two halves of 32 to bound register pressure.
  {
    const float* w1p   = W1 + (size_t)n*4096 + ln;
    const float* dembg = drug_table + (size_t)n*EDIM;   // uniform -> s_load
    int rbase = w4*25;
    float acc[25];
    {
      float w1c[32];
      #pragma unroll
      for (int e = 0; e < 32; ++e) w1c[e] = w1p[e*64] * dembg[e];
      #pragma unroll
      for (int rr = 0; rr < 25; ++rr) {
        const float* rp = rela_table + (size_t)(rbase + rr)*EDIM;  // uniform
        float a = 0.f;
        #pragma unroll
        for (int e = 0; e < 32; ++e) a = fmaf(rp[e], w1c[e], a);
        acc[rr] = a;
      }
    }
    {
      float w1c[32];
      #pragma unroll
      for (int e = 0; e < 32; ++e) w1c[e] = w1p[(e+32)*64] * dembg[e+32];
      #pragma unroll
      for (int rr = 0; rr < 25; ++rr) {
        const float* rp = rela_table + (size_t)(rbase + rr)*EDIM + 32;
        float a = acc[rr];
        #pragma unroll
        for (int e = 0; e < 32; ++e) a = fmaf(rp[e], w1c[e], a);
        g_s[(rbase + rr)*66 + ln] = a;
      }
    }
  }
  __syncthreads();

  // ---- phase 2: score[s] = sum_f relu(g[rel_s][f]+b1[s][f])*w2sum[f]+b2sum[s]
  // 4 lanes per s (fq covers f = jj*16 + fq*4 + c); 64 s per iteration, 16 its.
  {
    int fq = ln & 3;
    int sh = t >> 2;                         // 0..63
    float w2r[16];
    #pragma unroll
    for (int jj = 0; jj < 4; ++jj) {
      float4 v4 = *reinterpret_cast<const float4*>(w2sum_s + jj*16 + fq*4);
      w2r[jj*4+0] = v4.x; w2r[jj*4+1] = v4.y; w2r[jj*4+2] = v4.z; w2r[jj*4+3] = v4.w;
    }
    #pragma unroll
    for (int it = 0; it < 16; ++it) {
      int s   = it*64 + sh;
      int rel = adj_relation[(size_t)n*SNB + s];
      const float4* b1r = reinterpret_cast<const float4*>(b1 + (size_t)s*EDIM);
      const float2* g2  = reinterpret_cast<const float2*>(g_s + rel*66);
      float a2 = 0.f;
      #pragma unroll
      for (int jj = 0; jj < 4; ++jj) {
        float4 bv = b1r[jj*4 + fq];          // coalesced: 4 lanes cover 64B
        float2 ga = g2[jj*8 + fq*2];
        float2 gb = g2[jj*8 + fq*2 + 1];
        a2 = fmaf(fmaxf(ga.x + bv.x, 0.f), w2r[jj*4+0], a2);
        a2 = fmaf(fmaxf(ga.y + bv.y, 0.f), w2r[jj*4+1], a2);
        a2 = fmaf(fmaxf(gb.x + bv.z, 0.f), w2r[jj*4+2], a2);
        a2 = fmaf(fmaxf(gb.y + bv.w, 0.f), w2r[jj*4+3], a2);
      }
      a2 += __shfl_xor(a2, 1);
      a2 += __shfl_xor(a2, 2);
      if (fq == 0) score_s[s] = a2 + b2sum[s];
    }
  }
  __syncthreads();

  // ---- phase 3: softmax over 1024 (4 scores/thread; wave w4 owns chunks
  //      s = p*256 + w4*64 + ln, p = 0..3) ----------------------------------
  float av[4];
  {
    float sc[4];
    #pragma unroll
    for (int p = 0; p < 4; ++p) sc[p] = score_s[p*256 + t];
    float m = fmaxf(fmaxf(sc[0], sc[1]), fmaxf(sc[2], sc[3]));
    #pragma unroll
    for (int o = 32; o >= 1; o >>= 1) m = fmaxf(m, __shfl_xor(m, o));
    if (ln == 0) mred[w4] = m;
    __syncthreads();
    float M = fmaxf(fmaxf(mred[0], mred[1]), fmaxf(mred[2], mred[3]));
    float sum = 0.f;
    #pragma unroll
    for (int p = 0; p < 4; ++p) { av[p] = __expf(sc[p] - M); sum += av[p]; }
    #pragma unroll
    for (int o = 32; o >= 1; o >>= 1) sum += __shfl_xor(sum, o);
    if (ln == 0) mred[4 + w4] = sum;
    __syncthreads();
    float S = (mred[4] + mred[5]) + (mred[6] + mred[7]);
    float inv = 1.0f / S;
    #pragma unroll
    for (int p = 0; p < 4; ++p) av[p] *= inv;
  }

  // ---- phase 4: weighted_ent — each wave gathers its OWN active neighbors
  // (ballot per chunk; attn broadcast from owning lane via __shfl).
  {
    float acc4 = 0.f;
    const int* tails = adj_tail + (size_t)n*SNB;
    #pragma unroll
    for (int p = 0; p < 4; ++p) {
      unsigned long long mm = __ballot(av[p] > 2e-9f);
      int sbase = p*256 + w4*64;
      while (mm) {
        int b = __ffsll(mm) - 1; mm &= mm - 1;       // wave-uniform loop
        float a = __shfl(av[p], b);
        acc4 = fmaf(a, ent_table[(size_t)tails[sbase + b]*EDIM + ln], acc4);
      }
    }
    red_s[w4*64 + ln] = acc4;
  }
  __syncthreads();
  if (t < EDIM) {
    float w = ((red_s[t] + red_s[64 + t]) + (red_s[128 + t] + red_s[192 + t]));
    went_s[t] = w;
  }
  __syncthreads();

  // ---- phase 5: x = relu([went, demb] @ lin_W^T + lin_b) -------------------
  {
    float acc = 0.f;
    const float* lw = lin_W + (size_t)ln*128 + w4*32;
    #pragma unroll
    for (int k = 0; k < 32; ++k) {
      int kk = w4*32 + k;
      float cv = (kk < 64) ? went_s[kk] : demb_s[kk - 64];
      acc = fmaf(cv, lw[k], acc);
    }
    red_s[w4*64 + ln] = acc;
  }
  __syncthreads();
  if (t < EDIM) {
    float x = lin_b[t] + (red_s[t] + red_s[64 + t]) + (red_s[128 + t] + red_s[192 + t]);
    xbuf[(size_t)n*EDIM + t] = fmaxf(x, 0.f);
  }
}

// ---------------------------------------------------------------------------
// bn: one block per channel e — stats + apply fused
// ---------------------------------------------------------------------------
__global__ __launch_bounds__(256) void bn_kernel(
    const float* __restrict__ xbuf, const float* __restrict__ gamma,
    const float* __restrict__ beta, float* __restrict__ out)
{
  __shared__ float r1[4], r2[4];
  int e = blockIdx.x, t = threadIdx.x;
  float v[4];
  float s = 0.f, s2 = 0.f;
  #pragma unroll
  for (int k = 0; k < 4; ++k) {
    int nn = t + k*256;
    v[k] = (nn < NDRUG) ? xbuf[(size_t)nn*EDIM + e] : 0.f;
    s += v[k]; s2 += v[k]*v[k];
  }
  #pragma unroll
  for (int o = 32; o >= 1; o >>= 1) { s += __shfl_xor(s, o); s2 += __shfl_xor(s2, o); }
  if ((t & 63) == 0) { r1[t >> 6] = s; r2[t >> 6] = s2; }
  __syncthreads();
  float S  = r1[0] + r1[1] + r1[2] + r1[3];
  float S2 = r2[0] + r2[1] + r2[2] + r2[3];
  float mean = S / (float)NDRUG;
  float var  = S2 / (float)NDRUG - mean*mean;
  float sc   = gamma[e] * rsqrtf(var + 1e-5f);
  float sh   = beta[e] - mean*sc;
  #pragma unroll
  for (int k = 0; k < 4; ++k) {
    int nn = t + k*256;
    if (nn < NDRUG) out[(size_t)nn*EDIM + e] = v[k]*sc + sh;
  }
}

// ---------------------------------------------------------------------------
extern "C" void kernel_launch(void* const* d_in, const int* in_sizes, int n_in,
                              void* d_out, int out_size, void* d_ws, size_t ws_size,
                              hipStream_t stream)
{
  const int*   adj_tail   = (const int*)d_in[1];
  const int*   adj_rel    = (const int*)d_in[2];
  const float* drug_table = (const float*)d_in[3];
  const float* rela_table = (const float*)d_in[4];
  const float* ent_table  = (const float*)d_in[5];
  const float* W1         = (const float*)d_in[6];
  const float* b1         = (const float*)d_in[7];
  const float* W2         = (const float*)d_in[8];
  const float* b2         = (const float*)d_in[9];
  const float* lin_W      = (const float*)d_in[10];
  const float* lin_b      = (const float*)d_in[11];
  const float* gamma      = (const float*)d_in[12];
  const float* beta       = (const float*)d_in[13];

  float* ws    = (float*)d_ws;
  float* xbuf  = ws + XBUF_OFF;
  float* b2sum = ws + B2SUM_OFF;
  float* out   = (float*)d_out;

  hipLaunchKernelGGL(prep2, dim3(16), dim3(256), 0, stream, b2, b2sum);
  hipLaunchKernelGGL(gnn_main, dim3(NDRUG), dim3(256), 0, stream,
                     adj_tail, adj_rel, drug_table, rela_table, ent_table,
                     W1, W2, b1, lin_W, lin_b, b2sum, xbuf);
  hipLaunchKernelGGL(bn_kernel, dim3(EDIM), dim3(256), 0, stream,
                     xbuf, gamma, beta, out);
}